// Round 4
// baseline (151.412 us; speedup 1.0000x reference)
//
#include <hip/hip_runtime.h>
#include <hip/hip_fp16.h>

// Warp: trilinear grid_sample, padding_mode='zeros', align_corners=true.
// image: (B=2, C=1, H=128, W=128, D=128) fp32
// ddf:   (B=2, 3, H, W, D) fp32, voxel-unit displacements
// out:   (B, C, H, W, D) fp32
//
// R3 analysis: gather line-request rate through L1/TCC is the wall (HBM 11%,
// VALU 23%). Fix: LDS-staged tiling. Each block computes a 16^3 output tile;
// the 32^3 input region (halo 8, fp16, zeros outside volume) is staged into
// 64KB LDS with coalesced float4 reads, then the 8 trilinear taps are LDS
// reads with NO validity logic (staged zeros = zero-padding). Displacements
// beyond the halo (~0.1% of voxels, Gaussian sigma=3 tails) take an exact
// fp32 global-memory fallback path.

constexpr int H = 128, W = 128, D = 128;
constexpr int N = H * W * D;      // 2^21
constexpr int B = 2;
constexpr int TS = 16;            // output tile edge
constexpr int HA = 8;             // halo per side
constexpr int RS = TS + 2 * HA;   // 32 region edge
constexpr int RN = RS * RS * RS;  // 32768 voxels -> 64 KB fp16

typedef unsigned short us4 __attribute__((ext_vector_type(4)));

__global__ __launch_bounds__(256) void warp_tile_kernel(
    const float* __restrict__ image,
    const float* __restrict__ ddf,
    float* __restrict__ out)
{
    __shared__ __half tile[RN];   // 64 KB -> 2 blocks/CU

    int bid = blockIdx.x;
    int b  = bid >> 9;            // 512 tiles per batch
    int t3 = bid & 511;
    int tx0 = ((t3 >> 6) & 7) << 4;
    int ty0 = ((t3 >> 3) & 7) << 4;
    int tz0 = (t3 & 7) << 4;
    int ox = tx0 - HA, oy = ty0 - HA, oz = tz0 - HA;

    const float* img = image + ((size_t)b << 21);
    int t = threadIdx.x;

    // ---- stage 32^3 region as fp16 (zeros outside volume) ----
    // 8192 float4 slots; slot f: row = f>>3 (rx*32+ry), z-quad = (f&7)*4.
    // oz is a multiple of 4 minus 8 -> every float4 is fully in or fully out.
    unsigned short* tp = (unsigned short*)tile;
    for (int i = 0; i < 32; ++i) {
        int f   = i * 256 + t;
        int row = f >> 3;
        int zi  = (f & 7) << 2;
        int gx = ox + (row >> 5);
        int gy = oy + (row & 31);
        int gz = oz + zi;
        float4 v = make_float4(0.f, 0.f, 0.f, 0.f);
        if ((unsigned)gx < 128u && (unsigned)gy < 128u && (unsigned)gz < 128u)
            v = *(const float4*)(img + (gx << 14) + (gy << 7) + gz);
        us4 p;
        p.x = __half_as_ushort(__float2half_rn(v.x));
        p.y = __half_as_ushort(__float2half_rn(v.y));
        p.z = __half_as_ushort(__float2half_rn(v.z));
        p.w = __half_as_ushort(__float2half_rn(v.w));
        *(us4*)(tp + row * 32 + zi) = p;   // 8B-aligned ds_write_b64
    }
    __syncthreads();

    // ---- compute 16 outputs per thread ----
    int lz = t & 15;
    int ly = (t >> 4) & 15;
    const float* ddfb = ddf + (size_t)b * 3 * N;
    float* outb = out + ((size_t)b << 21);
    int yz = ((ty0 + ly) << 7) + (tz0 + lz);
    float py = (float)(ty0 + ly);
    float pz = (float)(tz0 + lz);

    for (int lx = 0; lx < 16; ++lx) {
        int lin = ((tx0 + lx) << 14) + yz;
        float x = (float)(tx0 + lx) + ddfb[lin];
        float y = py + ddfb[lin + N];
        float z = pz + ddfb[lin + 2 * N];

        float xf = floorf(x), yf = floorf(y), zf = floorf(z);
        float fx = x - xf, fy = y - yf, fz = z - zf;
        int x0 = (int)xf, y0 = (int)yf, z0 = (int)zf;
        int rx = x0 - ox, ry = y0 - oy, rz = z0 - oz;

        float acc;
        if ((unsigned)rx <= 30u && (unsigned)ry <= 30u && (unsigned)rz <= 30u) {
            // fast path: all 8 taps inside staged region; staged zeros
            // implement zero-padding, so weights need no masking.
            const __half* base = tile + ((rx << 5) + ry) * 32 + rz;
            float v000 = __half2float(base[0]);
            float v001 = __half2float(base[1]);
            float v010 = __half2float(base[32]);
            float v011 = __half2float(base[33]);
            float v100 = __half2float(base[1024]);
            float v101 = __half2float(base[1025]);
            float v110 = __half2float(base[1056]);
            float v111 = __half2float(base[1057]);
            float ax0 = 1.f - fx, ay0 = 1.f - fy, az0 = 1.f - fz;
            acc = ax0 * (ay0 * (az0 * v000 + fz * v001) +
                         fy  * (az0 * v010 + fz * v011)) +
                  fx  * (ay0 * (az0 * v100 + fz * v101) +
                         fy  * (az0 * v110 + fz * v111));
        } else {
            // rare fallback (~0.1% of voxels): exact fp32 global gather.
            int x1 = x0 + 1, y1 = y0 + 1, z1 = z0 + 1;
            bool vx0 = (unsigned)x0 < (unsigned)H;
            bool vx1 = (unsigned)x1 < (unsigned)H;
            bool vy0 = (unsigned)y0 < (unsigned)W;
            bool vy1 = (unsigned)y1 < (unsigned)W;
            bool vz0 = (unsigned)z0 < (unsigned)D;
            bool vz1 = (unsigned)z1 < (unsigned)D;
            float ax0 = vx0 ? (1.0f - fx) : 0.0f;
            float ax1 = vx1 ? fx          : 0.0f;
            float ay0 = vy0 ? (1.0f - fy) : 0.0f;
            float ay1 = vy1 ? fy          : 0.0f;
            float az0 = vz0 ? (1.0f - fz) : 0.0f;
            float az1 = vz1 ? fz          : 0.0f;
            int cx0 = vx0 ? x0 : 0;
            int cx1 = vx1 ? x1 : 0;
            int cy0 = vy0 ? y0 : 0;
            int cy1 = vy1 ? y1 : 0;
            int cz0 = vz0 ? z0 : 0;
            int cz1 = vz1 ? z1 : 0;
            int rx0 = cx0 << 14, rx1 = cx1 << 14;
            int ry0 = cy0 << 7,  ry1 = cy1 << 7;
            float v000 = img[rx0 + ry0 + cz0];
            float v001 = img[rx0 + ry0 + cz1];
            float v010 = img[rx0 + ry1 + cz0];
            float v011 = img[rx0 + ry1 + cz1];
            float v100 = img[rx1 + ry0 + cz0];
            float v101 = img[rx1 + ry0 + cz1];
            float v110 = img[rx1 + ry1 + cz0];
            float v111 = img[rx1 + ry1 + cz1];
            acc = ax0 * (ay0 * (az0 * v000 + az1 * v001) +
                         ay1 * (az0 * v010 + az1 * v011)) +
                  ax1 * (ay0 * (az0 * v100 + az1 * v101) +
                         ay1 * (az0 * v110 + az1 * v111));
        }
        outb[lin] = acc;
    }
}

extern "C" void kernel_launch(void* const* d_in, const int* in_sizes, int n_in,
                              void* d_out, int out_size, void* d_ws, size_t ws_size,
                              hipStream_t stream) {
    const float* image = (const float*)d_in[0];
    const float* ddf   = (const float*)d_in[1];
    float* out = (float*)d_out;

    int grid = B * 512;   // 1024 blocks, one 16^3 tile each
    warp_tile_kernel<<<grid, 256, 0, stream>>>(image, ddf, out);
}

// Round 5
// 131.377 us; speedup vs baseline: 1.1525x; 1.1525x over previous
//
#include <hip/hip_runtime.h>
#include <hip/hip_fp16.h>

// Warp: trilinear grid_sample, padding_mode='zeros', align_corners=true.
// image: (B=2, C=1, H=128, W=128, D=128) fp32
// ddf:   (B=2, 3, H, W, D) fp32, voxel-unit displacements
// out:   (B, C, H, W, D) fp32
//
// R4 post-mortem: LDS tiling removed the TA line-split wall, but 256-thread
// blocks + 64KB LDS gave only 8 waves/CU (occupancy 19%) -> latency-bound,
// VALU 10%. R5: 1024-thread blocks, same 64KB tile -> 2 blocks/CU = up to 32
// waves/CU (VGPR-capped ~24). ddf prefetched to registers before staging so
// its HBM latency overlaps the staging phase; nontemporal out stores.

constexpr int H = 128, W = 128, D = 128;
constexpr int N = H * W * D;      // 2^21
constexpr int B = 2;
constexpr int HA = 8;             // halo per side
constexpr int RS = 32;            // region edge (16 tile + 2*8 halo)
constexpr int RN = RS * RS * RS;  // 32768 voxels -> 64 KB fp16

typedef unsigned short us4 __attribute__((ext_vector_type(4)));

__global__ __launch_bounds__(1024, 6) void warp_tile_kernel(
    const float* __restrict__ image,
    const float* __restrict__ ddf,
    float* __restrict__ out)
{
    __shared__ __half tile[RN];   // 64 KB -> 2 blocks/CU (128/160 KB)

    int bid = blockIdx.x;
    int b  = bid >> 9;            // 512 tiles per batch
    int t3 = bid & 511;
    int tx0 = ((t3 >> 6) & 7) << 4;
    int ty0 = ((t3 >> 3) & 7) << 4;
    int tz0 = (t3 & 7) << 4;
    int ox = tx0 - HA, oy = ty0 - HA, oz = tz0 - HA;

    const float* img = image + ((size_t)b << 21);
    int t = threadIdx.x;          // 0..1023

    // ---- prefetch this thread's 12 ddf values (overlaps staging latency) ----
    int lz = t & 15;
    int ly = (t >> 4) & 15;
    int xb = (t >> 8) << 2;       // 4 consecutive x per thread
    const float* ddfb = ddf + (size_t)b * 3 * N;
    int yz = ((ty0 + ly) << 7) + (tz0 + lz);

    int   lins[4];
    float dx[4], dy[4], dz[4];
#pragma unroll
    for (int i = 0; i < 4; ++i) {
        int lin = ((tx0 + xb + i) << 14) + yz;
        lins[i] = lin;
        dx[i] = ddfb[lin];
        dy[i] = ddfb[lin + N];
        dz[i] = ddfb[lin + 2 * N];
    }

    // ---- stage 32^3 region as fp16 (zeros outside volume) ----
    // 8192 float4 slots; slot f: row = f>>3 (rx*32+ry), z-quad = (f&7)*4.
    // oz = 16k-8 -> each float4 is fully inside or fully outside the volume.
    unsigned short* tp = (unsigned short*)tile;
#pragma unroll
    for (int i = 0; i < 8; ++i) {
        int f   = i * 1024 + t;
        int row = f >> 3;
        int zi  = (f & 7) << 2;
        int gx = ox + (row >> 5);
        int gy = oy + (row & 31);
        int gz = oz + zi;
        float4 v = make_float4(0.f, 0.f, 0.f, 0.f);
        if ((unsigned)gx < 128u && (unsigned)gy < 128u && (unsigned)gz < 128u)
            v = *(const float4*)(img + (gx << 14) + (gy << 7) + gz);
        us4 p;
        p.x = __half_as_ushort(__float2half_rn(v.x));
        p.y = __half_as_ushort(__float2half_rn(v.y));
        p.z = __half_as_ushort(__float2half_rn(v.z));
        p.w = __half_as_ushort(__float2half_rn(v.w));
        *(us4*)(tp + row * 32 + zi) = p;   // 8B-aligned ds_write_b64
    }
    __syncthreads();

    // ---- compute 4 outputs per thread ----
    float* outb = out + ((size_t)b << 21);
    float py = (float)(ty0 + ly);
    float pz = (float)(tz0 + lz);

#pragma unroll
    for (int i = 0; i < 4; ++i) {
        float x = (float)(tx0 + xb + i) + dx[i];
        float y = py + dy[i];
        float z = pz + dz[i];

        float xf = floorf(x), yf = floorf(y), zf = floorf(z);
        float fx = x - xf, fy = y - yf, fz = z - zf;
        int x0 = (int)xf, y0 = (int)yf, z0 = (int)zf;
        int rx = x0 - ox, ry = y0 - oy, rz = z0 - oz;

        float acc;
        if ((unsigned)rx <= 30u && (unsigned)ry <= 30u && (unsigned)rz <= 30u) {
            // fast path: all 8 taps inside staged region; staged zeros
            // implement zero-padding, so weights need no masking.
            const __half* base = tile + ((rx << 5) + ry) * 32 + rz;
            float v000 = __half2float(base[0]);
            float v001 = __half2float(base[1]);
            float v010 = __half2float(base[32]);
            float v011 = __half2float(base[33]);
            float v100 = __half2float(base[1024]);
            float v101 = __half2float(base[1025]);
            float v110 = __half2float(base[1056]);
            float v111 = __half2float(base[1057]);
            float ax0 = 1.f - fx, ay0 = 1.f - fy, az0 = 1.f - fz;
            acc = ax0 * (ay0 * (az0 * v000 + fz * v001) +
                         fy  * (az0 * v010 + fz * v011)) +
                  fx  * (ay0 * (az0 * v100 + fz * v101) +
                         fy  * (az0 * v110 + fz * v111));
        } else {
            // rare fallback (~0.1% of voxels): exact fp32 global gather.
            int x1 = x0 + 1, y1 = y0 + 1, z1 = z0 + 1;
            bool vx0 = (unsigned)x0 < (unsigned)H;
            bool vx1 = (unsigned)x1 < (unsigned)H;
            bool vy0 = (unsigned)y0 < (unsigned)W;
            bool vy1 = (unsigned)y1 < (unsigned)W;
            bool vz0 = (unsigned)z0 < (unsigned)D;
            bool vz1 = (unsigned)z1 < (unsigned)D;
            float ax0 = vx0 ? (1.0f - fx) : 0.0f;
            float ax1 = vx1 ? fx          : 0.0f;
            float ay0 = vy0 ? (1.0f - fy) : 0.0f;
            float ay1 = vy1 ? fy          : 0.0f;
            float az0 = vz0 ? (1.0f - fz) : 0.0f;
            float az1 = vz1 ? fz          : 0.0f;
            int cx0 = vx0 ? x0 : 0;
            int cx1 = vx1 ? x1 : 0;
            int cy0 = vy0 ? y0 : 0;
            int cy1 = vy1 ? y1 : 0;
            int cz0 = vz0 ? z0 : 0;
            int cz1 = vz1 ? z1 : 0;
            int rx0 = cx0 << 14, rx1 = cx1 << 14;
            int ry0 = cy0 << 7,  ry1 = cy1 << 7;
            float v000 = img[rx0 + ry0 + cz0];
            float v001 = img[rx0 + ry0 + cz1];
            float v010 = img[rx0 + ry1 + cz0];
            float v011 = img[rx0 + ry1 + cz1];
            float v100 = img[rx1 + ry0 + cz0];
            float v101 = img[rx1 + ry0 + cz1];
            float v110 = img[rx1 + ry1 + cz0];
            float v111 = img[rx1 + ry1 + cz1];
            acc = ax0 * (ay0 * (az0 * v000 + az1 * v001) +
                         ay1 * (az0 * v010 + az1 * v011)) +
                  ax1 * (ay0 * (az0 * v100 + az1 * v101) +
                         ay1 * (az0 * v110 + az1 * v111));
        }
        __builtin_nontemporal_store(acc, &outb[lins[i]]);
    }
}

extern "C" void kernel_launch(void* const* d_in, const int* in_sizes, int n_in,
                              void* d_out, int out_size, void* d_ws, size_t ws_size,
                              hipStream_t stream) {
    const float* image = (const float*)d_in[0];
    const float* ddf   = (const float*)d_in[1];
    float* out = (float*)d_out;

    int grid = B * 512;   // 1024 blocks, one 16^3 tile each, 1024 threads
    warp_tile_kernel<<<grid, 1024, 0, stream>>>(image, ddf, out);
}